// Round 1
// baseline (31959.372 us; speedup 1.0000x reference)
//
#include <hip/hip_runtime.h>

// ============================================================================
// Fused seq2seq GRU encoder/decoder + attention, fp32, MI355X (gfx950).
//
// Design:
//  - grid = 256 blocks (1/CU), 256 threads (4 waves), ROWS=64 batch rows/block,
//    lane == row. Each block runs the WHOLE model for its rows; h0/h1 persist
//    in LDS across all 62 timesteps. No inter-block communication.
//  - Gate GEMMs: weights are read with wave-uniform indices -> scalar s_load
//    broadcast (VMEM pipe stays idle); x comes from LDS per-lane (odd strides
//    101/205 -> conflict-free). Gates are split j % 4 == wave, so each lane
//    holds the full (r,z,n) triple of its gates in registers -> in-register
//    GRU combine, no gi/gh LDS staging.
//  - Attention: scores[t] = enc[t]Β·(h1@attn_W) + h1Β·attn_b (energy never
//    materialized). enc stored transposed in ws: enc_t[t][d][row] (78.6 MB),
//    written/read by the same block (coalesced across lanes).
//  - Weights used directly from d_in (row-major == what the scalar GEMM wants);
//    only attn_W needs a transposed copy (tiny prep kernel into ws[0..10k)).
// ============================================================================

#define BB    16384   // batch
#define HH    100     // hidden
#define TE    12      // encoder steps
#define TDN   50      // decoder steps
#define ROWS  64      // rows per block (== lanes per wave)
#define XS    101     // LDS stride for [ROWS][100] buffers (odd -> no conflicts)
#define GS    205     // LDS stride for gin buffer [ROWS][200]
#define ENCT_OFF 16384  // float offset of enc_t inside ws (attn_t in [0,10000))

struct Params {
  const float *q, *p, *attn_b;
  const float *eWih0,*eWhh0,*ebih0,*ebhh0,*eWih1,*eWhh1,*ebih1,*ebhh1;
  const float *dWih0,*dWhh0,*dbih0,*dbhh0,*dWih1,*dWhh1,*dbih1,*dbhh1;
  const float *outW,*outb,*f1W,*f1b,*f2W,*f2b,*f3W,*f3b,*f4W,*f4b;
  float *ws;
  float *out;
};

__global__ void prep_attn_t(const float* __restrict__ attn_W, float* __restrict__ ws) {
  int i = blockIdx.x * 256 + threadIdx.x;
  if (i < HH * HH) {
    int d = i / HH, e = i % HH;
    ws[d * HH + e] = attn_W[e * HH + d];   // attn_t[d][e] = attn_W[e][d]
  }
}

__device__ __forceinline__ float sigf(float x)   { return 1.0f / (1.0f + __expf(-x)); }
__device__ __forceinline__ float tanhf_(float x) { float e = __expf(2.0f * x); return 1.0f - 2.0f / (e + 1.0f); }

// acc[m] = sum_k W[(wv+4m)*LDW + k] * xrow[k]   (m < NG; W index wave-uniform -> s_load)
template<int NG, int K, int LDW>
__device__ __forceinline__ void gemm_sw(const float* __restrict__ W,
                                        const float* xrow, int wv, float* acc) {
  #pragma unroll
  for (int m = 0; m < NG; ++m) acc[m] = 0.0f;
  #pragma unroll 1                      // keep body in I$; kc loop stays rolled
  for (int kc = 0; kc < K; kc += 25) {
    float xr[25];
    #pragma unroll
    for (int i = 0; i < 25; ++i) xr[i] = xrow[kc + i];
    #pragma unroll                       // full unroll: acc[] must stay in VGPRs
    for (int m = 0; m < NG; ++m) {
      const float* wr = W + (wv + 4 * m) * LDW + kc;
      float a = acc[m];
      #pragma unroll
      for (int i = 0; i < 25; ++i) a = fmaf(wr[i], xr[i], a);
      acc[m] = a;
    }
  }
}

// In-register GRU combine for this wave's gate residue class (n = wv + 4m).
template<bool WRITE_ENC>
__device__ __forceinline__ void gru_combine(const float* gi, const float* gh,
    const float* __restrict__ bih, const float* __restrict__ bhh,
    int wv, int lane, float (*hS)[XS], float* __restrict__ encT, int grow) {
  #pragma unroll
  for (int m = 0; m < 25; ++m) {
    const int n = wv + 4 * m;
    float ir  = gi[m]      + bih[n];
    float iz  = gi[m + 25] + bih[n + 100];
    float inn = gi[m + 50] + bih[n + 200];
    float hr  = gh[m]      + bhh[n];
    float hz  = gh[m + 25] + bhh[n + 100];
    float hn  = gh[m + 50] + bhh[n + 200];
    float r  = sigf(ir + hr);
    float z  = sigf(iz + hz);
    float ng = tanhf_(inn + r * hn);
    float hp = hS[lane][n];
    float hv = (1.0f - z) * ng + z * hp;
    hS[lane][n] = hv;
    if (WRITE_ENC) encT[n * BB + grow] = hv;   // enc_t[t][n][row], coalesced
  }
}

__global__ __launch_bounds__(256, 1) void fused_kernel(Params pr) {
  __shared__ float h0s[ROWS][XS];
  __shared__ float h1s[ROWS][XS];
  __shared__ float xb [ROWS][GS];   // encoder x / decoder gin = [p_t | ctx]
  __shared__ float gvb[ROWS][XS];   // gvec = h1 @ attn_W
  __shared__ float scb[ROWS][13];   // attention scores
  __shared__ float ob [ROWS][53];   // out_context result (50)

  const int tid  = threadIdx.x;
  const int lane = tid & 63;
  const int wv   = __builtin_amdgcn_readfirstlane(tid >> 6);
  const int r0   = blockIdx.x * ROWS;
  const int grow = r0 + lane;

  for (int it = tid; it < ROWS * XS; it += 256) {
    (&h0s[0][0])[it] = 0.0f;
    (&h1s[0][0])[it] = 0.0f;
  }
  __syncthreads();

  float gi[75], gh[75];

  // ===================== encoder: 12 steps =====================
  for (int t = 0; t < TE; ++t) {
    for (int it = tid; it < ROWS * HH; it += 256) {     // stage q[:, t, :]
      int r = it / HH, k = it % HH;
      xb[r][k] = pr.q[(size_t)(r0 + r) * (TE * HH) + t * HH + k];
    }
    __syncthreads();
    // layer 0
    gemm_sw<75, 100, 100>(pr.eWih0, &xb[lane][0],  wv, gi);
    gemm_sw<75, 100, 100>(pr.eWhh0, &h0s[lane][0], wv, gh);
    __syncthreads();
    gru_combine<false>(gi, gh, pr.ebih0, pr.ebhh0, wv, lane, h0s, nullptr, grow);
    __syncthreads();
    // layer 1 (+ write enc_t)
    gemm_sw<75, 100, 100>(pr.eWih1, &h0s[lane][0], wv, gi);
    gemm_sw<75, 100, 100>(pr.eWhh1, &h1s[lane][0], wv, gh);
    __syncthreads();
    gru_combine<true>(gi, gh, pr.ebih1, pr.ebhh1, wv, lane, h1s,
                      pr.ws + ENCT_OFF + (size_t)t * HH * BB, grow);
    __syncthreads();
  }

  const float* encT  = pr.ws + ENCT_OFF;
  const float* attnT = pr.ws;

  // ===================== decoder: 50 steps =====================
  for (int t = 0; t < TDN; ++t) {
    // A: gvec = h1 @ attn_W  (gate dim = d, mod-4 across waves)
    {
      float ga[25];
      gemm_sw<25, 100, 100>(attnT, &h1s[lane][0], wv, ga);
      #pragma unroll
      for (int m = 0; m < 25; ++m) gvb[lane][wv + 4 * m] = ga[m];
    }
    float cb = 0.0f;                                   // h1 . attn_b
    #pragma unroll 4
    for (int e = 0; e < HH; ++e) cb = fmaf(h1s[lane][e], pr.attn_b[e], cb);
    __syncthreads();

    // B: scores (3 timesteps per wave), per-lane row
    {
      const int tb = 3 * wv;
      float sc0 = cb, sc1 = cb, sc2 = cb;
      #pragma unroll 1
      for (int dc = 0; dc < HH; dc += 25) {
        float gv[25];
        #pragma unroll
        for (int i = 0; i < 25; ++i) gv[i] = gvb[lane][dc + i];
        #pragma unroll
        for (int i = 0; i < 25; ++i) {
          sc0 = fmaf(gv[i], encT[(size_t)((tb + 0) * HH + dc + i) * BB + grow], sc0);
          sc1 = fmaf(gv[i], encT[(size_t)((tb + 1) * HH + dc + i) * BB + grow], sc1);
          sc2 = fmaf(gv[i], encT[(size_t)((tb + 2) * HH + dc + i) * BB + grow], sc2);
        }
      }
      scb[lane][tb + 0] = sc0;
      scb[lane][tb + 1] = sc1;
      scb[lane][tb + 2] = sc2;
    }
    __syncthreads();

    // softmax over 12 (per-lane, redundant across waves - cheap)
    float aw[TE];
    {
      float mx = -1e30f;
      #pragma unroll
      for (int k = 0; k < TE; ++k) { float v = scb[lane][k]; aw[k] = v; mx = fmaxf(mx, v); }
      float s = 0.0f;
      #pragma unroll
      for (int k = 0; k < TE; ++k) { float e = __expf(aw[k] - mx); aw[k] = e; s += e; }
      float inv = 1.0f / s;
      #pragma unroll
      for (int k = 0; k < TE; ++k) aw[k] *= inv;
    }

    // C: ctx (25 dims per wave) -> xb[.][100..199]
    {
      const int db = 25 * wv;
      float cx[25];
      #pragma unroll
      for (int i = 0; i < 25; ++i) cx[i] = 0.0f;
      #pragma unroll
      for (int k = 0; k < TE; ++k) {
        float a = aw[k];
        #pragma unroll
        for (int i = 0; i < 25; ++i)
          cx[i] = fmaf(a, encT[(size_t)(k * HH + db + i) * BB + grow], cx[i]);
      }
      #pragma unroll
      for (int i = 0; i < 25; ++i) xb[lane][HH + db + i] = cx[i];
    }
    // D: stage p[:, t, :] -> xb[.][0..99]  (disjoint columns vs C, no sync needed)
    for (int it = tid; it < ROWS * HH; it += 256) {
      int r = it / HH, k = it % HH;
      xb[r][k] = pr.p[(size_t)(r0 + r) * (TDN * HH) + t * HH + k];
    }
    __syncthreads();

    // E: GRU layer 0 (input = [p_t | ctx], K=200)
    gemm_sw<75, 200, 200>(pr.dWih0, &xb[lane][0],  wv, gi);
    gemm_sw<75, 100, 100>(pr.dWhh0, &h0s[lane][0], wv, gh);
    __syncthreads();
    gru_combine<false>(gi, gh, pr.dbih0, pr.dbhh0, wv, lane, h0s, nullptr, grow);
    __syncthreads();

    // F: GRU layer 1
    gemm_sw<75, 100, 100>(pr.dWih1, &h0s[lane][0], wv, gi);
    gemm_sw<75, 100, 100>(pr.dWhh1, &h1s[lane][0], wv, gh);
    __syncthreads();
    gru_combine<false>(gi, gh, pr.dbih1, pr.dbhh1, wv, lane, h1s, nullptr, grow);
    __syncthreads();
  }

  // ===================== out_context (last step only) =====================
  {
    float acc[13];
    #pragma unroll
    for (int m = 0; m < 13; ++m) acc[m] = 0.0f;
    #pragma unroll 1
    for (int half = 0; half < 2; ++half) {
      const float* xsrc = half ? &xb[lane][HH] : &h1s[lane][0];  // [h1 | ctx]
      #pragma unroll 1
      for (int kc = 0; kc < HH; kc += 25) {
        float xr[25];
        #pragma unroll
        for (int i = 0; i < 25; ++i) xr[i] = xsrc[kc + i];
        #pragma unroll
        for (int m = 0; m < 13; ++m) {
          const int o = wv + 4 * m;
          if (o < 50) {
            const float* wr = pr.outW + o * 200 + half * HH + kc;
            float a = acc[m];
            #pragma unroll
            for (int i = 0; i < 25; ++i) a = fmaf(wr[i], xr[i], a);
            acc[m] = a;
          }
        }
      }
    }
    #pragma unroll
    for (int m = 0; m < 13; ++m) {
      const int o = wv + 4 * m;
      if (o < 50) ob[lane][o] = fmaxf(acc[m] + pr.outb[o], 0.0f);
    }
  }
  __syncthreads();

  // ===================== final MLP + softmax (wave 0, per-lane row) ========
  if (wv == 0) {
    float s0[50];
    #pragma unroll
    for (int i = 0; i < 50; ++i) s0[i] = ob[lane][i];
    float s1[25];
    #pragma unroll 1
    for (int o = 0; o < 25; ++o) {
      float a = pr.f1b[o];
      #pragma unroll
      for (int k = 0; k < 50; ++k) a = fmaf(pr.f1W[o * 50 + k], s0[k], a);
      s1[o] = fmaxf(a, 0.0f);
    }
    float s2[10];
    #pragma unroll 1
    for (int o = 0; o < 10; ++o) {
      float a = pr.f2b[o];
      #pragma unroll
      for (int k = 0; k < 25; ++k) a = fmaf(pr.f2W[o * 25 + k], s1[k], a);
      s2[o] = fmaxf(a, 0.0f);
    }
    float s3[4];
    #pragma unroll
    for (int o = 0; o < 4; ++o) {
      float a = pr.f3b[o];
      #pragma unroll
      for (int k = 0; k < 10; ++k) a = fmaf(pr.f3W[o * 10 + k], s2[k], a);
      s3[o] = fmaxf(a, 0.0f);
    }
    float l0 = pr.f4b[0], l1 = pr.f4b[1];
    #pragma unroll
    for (int k = 0; k < 4; ++k) {
      l0 = fmaf(pr.f4W[k],     s3[k], l0);
      l1 = fmaf(pr.f4W[4 + k], s3[k], l1);
    }
    float mx = fmaxf(l0, l1);
    float e0 = __expf(l0 - mx), e1 = __expf(l1 - mx);
    float inv = 1.0f / (e0 + e1);
    pr.out[(size_t)grow * 2 + 0] = e0 * inv;
    pr.out[(size_t)grow * 2 + 1] = e1 * inv;
  }
}

extern "C" void kernel_launch(void* const* d_in, const int* in_sizes, int n_in,
                              void* d_out, int out_size, void* d_ws, size_t ws_size,
                              hipStream_t stream) {
  Params pr;
  pr.q      = (const float*)d_in[0];
  pr.p      = (const float*)d_in[1];
  // d_in[2] = attn_W (transposed by prep kernel into ws)
  pr.attn_b = (const float*)d_in[3];
  pr.eWih0  = (const float*)d_in[4];
  pr.eWhh0  = (const float*)d_in[5];
  pr.ebih0  = (const float*)d_in[6];
  pr.ebhh0  = (const float*)d_in[7];
  pr.eWih1  = (const float*)d_in[8];
  pr.eWhh1  = (const float*)d_in[9];
  pr.ebih1  = (const float*)d_in[10];
  pr.ebhh1  = (const float*)d_in[11];
  pr.dWih0  = (const float*)d_in[12];
  pr.dWhh0  = (const float*)d_in[13];
  pr.dbih0  = (const float*)d_in[14];
  pr.dbhh0  = (const float*)d_in[15];
  pr.dWih1  = (const float*)d_in[16];
  pr.dWhh1  = (const float*)d_in[17];
  pr.dbih1  = (const float*)d_in[18];
  pr.dbhh1  = (const float*)d_in[19];
  pr.outW   = (const float*)d_in[20];
  pr.outb   = (const float*)d_in[21];
  pr.f1W    = (const float*)d_in[22];
  pr.f1b    = (const float*)d_in[23];
  pr.f2W    = (const float*)d_in[24];
  pr.f2b    = (const float*)d_in[25];
  pr.f3W    = (const float*)d_in[26];
  pr.f3b    = (const float*)d_in[27];
  pr.f4W    = (const float*)d_in[28];
  pr.f4b    = (const float*)d_in[29];
  pr.ws     = (float*)d_ws;
  pr.out    = (float*)d_out;

  prep_attn_t<<<40, 256, 0, stream>>>((const float*)d_in[2], (float*)d_ws);
  fused_kernel<<<BB / ROWS, 256, 0, stream>>>(pr);
}